// Round 10
// baseline (385.070 us; speedup 1.0000x reference)
//
#include <hip/hip_runtime.h>
#include <hip/hip_bf16.h>

#define B_ 8
#define S_ 2048
#define H_ 256
#define Z_ 64
#define CHK 32            // k per staged chunk
#define NQCH 16           // chunks per 512-k quarter
#define BS (B_*S_)        // 16384 rows
#define PSLD 40           // Ps row stride (shorts): unit-stride 5 -> conflict-free b128

typedef short bf16x8 __attribute__((ext_vector_type(8)));
typedef float f32x4 __attribute__((ext_vector_type(4)));

__device__ __forceinline__ unsigned short f2bf(float f) {
  __hip_bfloat16 h = __float2bfloat16(f);
  return *reinterpret_cast<unsigned short*>(&h);
}
__device__ __forceinline__ float bf2f(unsigned short u) {
  __hip_bfloat16 h;
  *reinterpret_cast<unsigned short*>(&h) = u;
  return __bfloat162float(h);
}

// async global->LDS DMA, 16 B/lane
__device__ __forceinline__ void gl_lds16(const void* g, void* l) {
  __builtin_amdgcn_global_load_lds(
      (const __attribute__((address_space(1))) unsigned int*)(uintptr_t)g,
      (__attribute__((address_space(3))) unsigned int*)(uintptr_t)l,
      16, 0, 0);
}

// ---------------------------------------------------------------------------
// k0: per-batch encoder-part projections
__global__ __launch_bounds__(256) void k0_base(
    const float* __restrict__ enc, const float* __restrict__ Wq,
    const float* __restrict__ Wk, const float* __restrict__ Wv,
    float* __restrict__ q0, float* __restrict__ k0, float* __restrict__ v0) {
  int b = blockIdx.x;
  int h = threadIdx.x;
  __shared__ float encs[H_];
  encs[h] = enc[b*H_ + h] + enc[B_*H_ + b*H_ + h];
  __syncthreads();
  float aq = 0.f, ak = 0.f, av = 0.f;
  #pragma unroll 4
  for (int d = 0; d < H_; d++) {
    float e = encs[d];
    aq = fmaf(e, Wq[d*H_ + h], aq);
    ak = fmaf(e, Wk[d*H_ + h], ak);
    av = fmaf(e, Wv[d*H_ + h], av);
  }
  q0[b*H_ + h] = aq;
  k0[b*H_ + h] = ak;
  v0[b*H_ + h] = av;
}

// ---------------------------------------------------------------------------
// k1: z-part projection + hi/lo bf16 split for Q,K; V -> bf16 transposed Vt
__global__ __launch_bounds__(256) void k1_prep(
    const float* __restrict__ z, const float* __restrict__ Wq,
    const float* __restrict__ Wk, const float* __restrict__ Wv,
    const float* __restrict__ q0, const float* __restrict__ k0b, const float* __restrict__ v0,
    unsigned short* __restrict__ Qhi, unsigned short* __restrict__ Qlo,
    unsigned short* __restrict__ Khi, unsigned short* __restrict__ Klo,
    unsigned short* __restrict__ Vt) {
  int b  = blockIdx.x >> 7;
  int st = blockIdx.x & 127;
  int tid = threadIdx.x;      // tid = h
  __shared__ float zs[16*Z_];
  __shared__ float vbuf[16][H_];
  {
    const float4* zp = reinterpret_cast<const float4*>(z + ((size_t)b*S_ + st*16)*Z_);
    reinterpret_cast<float4*>(zs)[tid] = zp[tid];
  }
  __syncthreads();
  float bq = q0[b*H_ + tid], bk = k0b[b*H_ + tid], bv = v0[b*H_ + tid];
  float accq[16], acck[16], accv[16];
  #pragma unroll
  for (int s = 0; s < 16; s++) { accq[s] = bq; acck[s] = bk; accv[s] = bv; }
  #pragma unroll 2
  for (int z0 = 0; z0 < Z_; z0 += 8) {
    float wq[8], wk[8], wv[8];
    #pragma unroll
    for (int j = 0; j < 8; j++) {
      wq[j] = Wq[(H_+z0+j)*H_ + tid];
      wk[j] = Wk[(H_+z0+j)*H_ + tid];
      wv[j] = Wv[(H_+z0+j)*H_ + tid];
    }
    #pragma unroll
    for (int j = 0; j < 8; j++) {
      #pragma unroll
      for (int s = 0; s < 16; s++) {
        float zz = zs[s*Z_ + z0 + j];
        accq[s] = fmaf(zz, wq[j], accq[s]);
        acck[s] = fmaf(zz, wk[j], acck[s]);
        accv[s] = fmaf(zz, wv[j], accv[s]);
      }
    }
  }
  #pragma unroll
  for (int s = 0; s < 16; s++) {
    size_t row = ((size_t)b*S_ + st*16 + s)*H_ + tid;
    unsigned short qh = f2bf(accq[s]);
    Qhi[row] = qh;
    Qlo[row] = f2bf(accq[s] - bf2f(qh));
    unsigned short kh = f2bf(acck[s]);
    Khi[row] = kh;
    Klo[row] = f2bf(acck[s] - bf2f(kh));
    vbuf[s][tid] = accv[s];
  }
  __syncthreads();
  unsigned int pk[8];
  #pragma unroll
  for (int j = 0; j < 8; j++) {
    pk[j] = (unsigned int)f2bf(vbuf[2*j][tid]) |
            ((unsigned int)f2bf(vbuf[2*j+1][tid]) << 16);
  }
  uint4* vt4 = reinterpret_cast<uint4*>(Vt + ((size_t)b*H_ + tid)*S_ + st*16);
  vt4[0] = make_uint4(pk[0], pk[1], pk[2], pk[3]);
  vt4[1] = make_uint4(pk[4], pk[5], pk[6], pk[7]);
}

// ---------------------------------------------------------------------------
// k2: flash attention. Block = 128 q rows (wave w owns 32 rows = 2 q-tiles,
// amortizing every K LDS read over 2 MFMAs) x one 512-k quarter. K/V fully
// double-buffered via async DMA (1 barrier/chunk, full overlap). 1 block/CU
// (launch_bounds(256,1): 512-reg budget, ~330 VGPRs, no spill). Raw fp32
// scores to attn; only running max kept (denominator deferred to k3).
__global__ __launch_bounds__(256, 1) void k2_flash(
    const unsigned short* __restrict__ Qhi, const unsigned short* __restrict__ Qlo,
    const unsigned short* __restrict__ Khi, const unsigned short* __restrict__ Klo,
    const unsigned short* __restrict__ Vt, const int* __restrict__ mask,
    float* __restrict__ attn, float* __restrict__ Mq,
    unsigned short* __restrict__ Opart) {
  int bb    = blockIdx.x;
  int b     = bb & 7;           // batch = XCD (L2 locality)
  int strip = (bb >> 3) & 15;   // 16 strips of 128 q
  int kq    = bb >> 7;          // k-quarter 0..3
  int qb    = strip*128;
  int k0q   = kq*512;
  int tid  = threadIdx.x;
  int wave = tid >> 6;
  int lane = tid & 63;
  int l15  = lane & 15;
  int quad = lane >> 4;
  int qw   = qb + wave*32;      // this wave's 32-row q base

  __shared__ __align__(16) unsigned short KhiL[2][32*256];   // 32 KB, XOR-swizzled
  __shared__ __align__(16) unsigned short KloL[2][32*256];   // 32 KB, XOR-swizzled
  __shared__ __align__(16) unsigned short VtL[2][256*32];    // 32 KB, XOR-swizzled
  __shared__ __align__(16) unsigned short Ps[4][2][16*PSLD]; // 10 KB
  // 106 KB -> 1 block/CU (by design)

  const unsigned short* KhiB = Khi + (size_t)b*S_*H_;
  const unsigned short* KloB = Klo + (size_t)b*S_*H_;
  const unsigned short* VtB  = Vt  + (size_t)b*H_*S_;

  int sub = lane >> 5;          // K-DMA: row pair within instr
  int c5  = lane & 31;          // K-DMA: 16B slot within 512B row
  int hl  = lane >> 2;          // V-DMA: h within 16-row group
  int jj  = lane & 3;           // V-DMA: 16B slot within 64B row

  auto dma_chunk = [&](int c) {
    int buf = c & 1;
    int kc = k0q + c*CHK;
    #pragma unroll
    for (int t = 0; t < 4; t++) {
      int i = wave*4 + t;                 // 16 x 1KB instrs over 4 waves
      int row = i*2 + sub;                // K row 0..31
      size_t gs = (size_t)(kc + row)*H_ + ((c5 ^ row)*8);  // swizzled
      gl_lds16(KhiB + gs, &KhiL[buf][i*512]);
      gl_lds16(KloB + gs, &KloL[buf][i*512]);
    }
    #pragma unroll
    for (int t = 0; t < 4; t++) {
      int i = wave*4 + t;
      int h = i*16 + hl;
      gl_lds16(VtB + (size_t)h*S_ + kc + ((jj ^ (hl & 3))*8), &VtL[buf][i*512]);
    }
  };

  // Q fragments for 2 q-tiles: A[m=l15][k=quad*8+j]
  bf16x8 qh[2][8], ql[2][8];
  #pragma unroll
  for (int qt = 0; qt < 2; qt++) {
    const unsigned short* qhp = Qhi + ((size_t)b*S_ + qw + qt*16 + l15)*H_ + quad*8;
    const unsigned short* qlp = Qlo + ((size_t)b*S_ + qw + qt*16 + l15)*H_ + quad*8;
    #pragma unroll
    for (int dc = 0; dc < 8; dc++) {
      qh[qt][dc] = *reinterpret_cast<const bf16x8*>(qhp + dc*32);
      ql[qt][dc] = *reinterpret_cast<const bf16x8*>(qlp + dc*32);
    }
  }
  int mrow[2][4];
  #pragma unroll
  for (int qt = 0; qt < 2; qt++)
    #pragma unroll
    for (int r = 0; r < 4; r++) mrow[qt][r] = mask[b*S_ + qw + qt*16 + quad*4 + r];

  f32x4 acc_o[2][16];
  #pragma unroll
  for (int qt = 0; qt < 2; qt++)
    #pragma unroll
    for (int ht = 0; ht < 16; ht++) acc_o[qt][ht] = (f32x4){0.f, 0.f, 0.f, 0.f};
  float m_run[2][4] = {{-1e30f,-1e30f,-1e30f,-1e30f},{-1e30f,-1e30f,-1e30f,-1e30f}};

  dma_chunk(0);
  __syncthreads();     // vmcnt drain -> chunk 0 resident

  for (int c = 0; c < NQCH; c++) {
    if (c+1 < NQCH) dma_chunk(c+1);     // into other buffer; lands during compute
    int buf = c & 1;
    int kc  = k0q + c*CHK;
    // ---- S tiles [2x 16q x 32k]: Qhi*Khi + Qlo*Khi + Qhi*Klo ----
    f32x4 sacc[2][2];
    #pragma unroll
    for (int kt = 0; kt < 2; kt++) {
      int row = kt*16 + l15;
      const unsigned short* khb = &KhiL[buf][row*256];
      const unsigned short* klb = &KloL[buf][row*256];
      f32x4 a0[2], a1[2];
      #pragma unroll
      for (int qt = 0; qt < 2; qt++) {
        a0[qt] = (f32x4){0.f,0.f,0.f,0.f};
        a1[qt] = (f32x4){0.f,0.f,0.f,0.f};
      }
      #pragma unroll
      for (int dc = 0; dc < 8; dc += 2) {
        int s0 = ((dc*4 + quad) ^ row) * 8;
        int s1 = (((dc+1)*4 + quad) ^ row) * 8;
        bf16x8 kh0 = *reinterpret_cast<const bf16x8*>(khb + s0);
        bf16x8 kl0 = *reinterpret_cast<const bf16x8*>(klb + s0);
        bf16x8 kh1 = *reinterpret_cast<const bf16x8*>(khb + s1);
        bf16x8 kl1 = *reinterpret_cast<const bf16x8*>(klb + s1);
        #pragma unroll
        for (int qt = 0; qt < 2; qt++) {   // each K frag feeds both q-tiles
          a0[qt] = __builtin_amdgcn_mfma_f32_16x16x32_bf16(qh[qt][dc],   kh0, a0[qt], 0, 0, 0);
          a1[qt] = __builtin_amdgcn_mfma_f32_16x16x32_bf16(qh[qt][dc+1], kh1, a1[qt], 0, 0, 0);
          a0[qt] = __builtin_amdgcn_mfma_f32_16x16x32_bf16(ql[qt][dc],   kh0, a0[qt], 0, 0, 0);
          a1[qt] = __builtin_amdgcn_mfma_f32_16x16x32_bf16(ql[qt][dc+1], kh1, a1[qt], 0, 0, 0);
          a0[qt] = __builtin_amdgcn_mfma_f32_16x16x32_bf16(qh[qt][dc],   kl0, a0[qt], 0, 0, 0);
          a1[qt] = __builtin_amdgcn_mfma_f32_16x16x32_bf16(qh[qt][dc+1], kl1, a1[qt], 0, 0, 0);
        }
      }
      #pragma unroll
      for (int qt = 0; qt < 2; qt++) sacc[qt][kt] = a0[qt] + a1[qt];
    }
    // ---- softmax state: running max only (denominator deferred to k3) ----
    float p[2][2][4], alpha[2][4];
    bool resc = false;
    #pragma unroll
    for (int qt = 0; qt < 2; qt++) {
      #pragma unroll
      for (int r = 0; r < 4; r++) {
        float se0 = mrow[qt][r] ? sacc[qt][0][r]*0.0625f : -1e9f;
        float se1 = mrow[qt][r] ? sacc[qt][1][r]*0.0625f : -1e9f;
        float ml = fmaxf(se0, se1);
        ml = fmaxf(ml, __shfl_xor(ml, 1));
        ml = fmaxf(ml, __shfl_xor(ml, 2));
        ml = fmaxf(ml, __shfl_xor(ml, 4));
        ml = fmaxf(ml, __shfl_xor(ml, 8));
        float mnew = fmaxf(m_run[qt][r], ml);
        alpha[qt][r] = __expf(m_run[qt][r] - mnew);
        p[qt][0][r] = __expf(se0 - mnew);
        p[qt][1][r] = __expf(se1 - mnew);
        m_run[qt][r] = mnew;
        resc |= (alpha[qt][r] < 1.f);
        // raw scores straight out (coalesced 16-lane rows)
        attn[((size_t)b*S_ + qw + qt*16 + quad*4 + r)*S_ + kc + l15]      = se0;
        attn[((size_t)b*S_ + qw + qt*16 + quad*4 + r)*S_ + kc + 16 + l15] = se1;
      }
    }
    if (__any(resc)) {                   // skip 128 mults once max settles
      #pragma unroll
      for (int qt = 0; qt < 2; qt++)
        #pragma unroll
        for (int ht = 0; ht < 16; ht++) {
          acc_o[qt][ht][0] *= alpha[qt][0];
          acc_o[qt][ht][1] *= alpha[qt][1];
          acc_o[qt][ht][2] *= alpha[qt][2];
          acc_o[qt][ht][3] *= alpha[qt][3];
        }
    }
    // ---- bf16 p' to Ps (wave-private) ----
    #pragma unroll
    for (int qt = 0; qt < 2; qt++)
      #pragma unroll
      for (int kt = 0; kt < 2; kt++)
        #pragma unroll
        for (int r = 0; r < 4; r++)
          Ps[wave][qt][(quad*4 + r)*PSLD + kt*16 + l15] = f2bf(p[qt][kt][r]);
    // ---- AV: each V frag feeds both q-tiles ----
    bf16x8 pa0 = *reinterpret_cast<const bf16x8*>(&Ps[wave][0][l15*PSLD + quad*8]);
    bf16x8 pa1 = *reinterpret_cast<const bf16x8*>(&Ps[wave][1][l15*PSLD + quad*8]);
    #pragma unroll
    for (int ht = 0; ht < 16; ht++) {
      bf16x8 v = *reinterpret_cast<const bf16x8*>(
          &VtL[buf][(ht*16 + l15)*32 + ((quad ^ (l15 & 3))*8)]);
      acc_o[0][ht] = __builtin_amdgcn_mfma_f32_16x16x32_bf16(pa0, v, acc_o[0][ht], 0, 0, 0);
      acc_o[1][ht] = __builtin_amdgcn_mfma_f32_16x16x32_bf16(pa1, v, acc_o[1][ht], 0, 0, 0);
    }
    __syncthreads();   // single barrier: readers done + DMA(c+1) drained
  }

  // ---- tail: partial max + unnormalized partial O (bf16) ----
  if (l15 == 0) {
    #pragma unroll
    for (int qt = 0; qt < 2; qt++)
      #pragma unroll
      for (int r = 0; r < 4; r++)
        Mq[kq*BS + b*S_ + qw + qt*16 + quad*4 + r] = m_run[qt][r];
  }
  #pragma unroll
  for (int qt = 0; qt < 2; qt++)
    #pragma unroll
    for (int ht = 0; ht < 16; ht++)
      #pragma unroll
      for (int r = 0; r < 4; r++) {
        size_t idx = ((size_t)kq*BS + b*S_ + qw + qt*16 + quad*4 + r)*H_ + ht*16 + l15;
        Opart[idx] = f2bf(acc_o[qt][ht][r]);
      }
}

// ---------------------------------------------------------------------------
// k3: one block per row. m = max over quarters; single pass over the raw-score
// row computes l = sum exp(se-m) (block reduction), then writes attn = e/l and
// out = sum_q exp(m_q - m) * O_q / l.
__global__ __launch_bounds__(256) void k3_combine(
    const float* __restrict__ Mq, const unsigned short* __restrict__ Opart,
    float* __restrict__ attn, float* __restrict__ outp) {
  int gr  = blockIdx.x;     // b*S_ + q
  int tid = threadIdx.x;
  int lane = tid & 63, wv = tid >> 6;
  __shared__ float red[4];
  float m0 = Mq[gr], m1 = Mq[BS + gr], m2 = Mq[2*BS + gr], m3 = Mq[3*BS + gr];
  float m = fmaxf(fmaxf(m0, m1), fmaxf(m2, m3));
  float4* pa = reinterpret_cast<float4*>(attn + (size_t)gr*S_ + tid*8);
  float4 x0 = pa[0], x1 = pa[1];
  x0.x = __expf(x0.x - m); x0.y = __expf(x0.y - m);
  x0.z = __expf(x0.z - m); x0.w = __expf(x0.w - m);
  x1.x = __expf(x1.x - m); x1.y = __expf(x1.y - m);
  x1.z = __expf(x1.z - m); x1.w = __expf(x1.w - m);
  float ps = x0.x + x0.y + x0.z + x0.w + x1.x + x1.y + x1.z + x1.w;
  ps += __shfl_xor(ps, 1);  ps += __shfl_xor(ps, 2);
  ps += __shfl_xor(ps, 4);  ps += __shfl_xor(ps, 8);
  ps += __shfl_xor(ps, 16); ps += __shfl_xor(ps, 32);
  if (lane == 0) red[wv] = ps;
  __syncthreads();
  float il = 1.f / (red[0] + red[1] + red[2] + red[3]);
  x0.x *= il; x0.y *= il; x0.z *= il; x0.w *= il;
  x1.x *= il; x1.y *= il; x1.z *= il; x1.w *= il;
  pa[0] = x0; pa[1] = x1;
  float o = __expf(m0 - m)*bf2f(Opart[(size_t)gr*H_ + tid])
          + __expf(m1 - m)*bf2f(Opart[((size_t)BS + gr)*H_ + tid])
          + __expf(m2 - m)*bf2f(Opart[((size_t)2*BS + gr)*H_ + tid])
          + __expf(m3 - m)*bf2f(Opart[((size_t)3*BS + gr)*H_ + tid]);
  outp[(size_t)gr*H_ + tid] = o * il;
}

// ---------------------------------------------------------------------------
extern "C" void kernel_launch(void* const* d_in, const int* in_sizes, int n_in,
                              void* d_out, int out_size, void* d_ws, size_t ws_size,
                              hipStream_t stream) {
  const float* enc = (const float*)d_in[0];
  // d_in[1] = decoder_hidden_state: unused by the reference
  const float* z   = (const float*)d_in[2];
  const int* mask  = (const int*)d_in[3];
  const float* Wq  = (const float*)d_in[4];
  const float* Wk  = (const float*)d_in[5];
  const float* Wv  = (const float*)d_in[6];

  char* ws = (char*)d_ws;
  const size_t MB = 1024*1024;
  unsigned short* Qhi = (unsigned short*)(ws);
  unsigned short* Qlo = (unsigned short*)(ws +  8*MB);
  unsigned short* Khi = (unsigned short*)(ws + 16*MB);
  unsigned short* Klo = (unsigned short*)(ws + 24*MB);
  unsigned short* Vt  = (unsigned short*)(ws + 32*MB);
  float* q0 = (float*)(ws + 40*MB);
  float* k0 = q0 + B_*H_;
  float* v0 = k0 + B_*H_;
  float* Mq = (float*)(ws + 41*MB);                       // [4][B*S]
  unsigned short* Opart = (unsigned short*)(ws + 42*MB);  // [4][B*S][H] bf16 = 32 MB

  float* outp = (float*)d_out;
  float* attn = outp + (size_t)B_*S_*H_;

  k0_base<<<B_, 256, 0, stream>>>(enc, Wq, Wk, Wv, q0, k0, v0);
  k1_prep<<<B_*(S_/16), 256, 0, stream>>>(z, Wq, Wk, Wv, q0, k0, v0,
                                          Qhi, Qlo, Khi, Klo, Vt);
  k2_flash<<<B_*(S_/128)*4, 256, 0, stream>>>(Qhi, Qlo, Khi, Klo, Vt, mask,
                                              attn, Mq, Opart);
  k3_combine<<<B_*S_, 256, 0, stream>>>(Mq, Opart, attn, outp);
}

// Round 11
// 337.984 us; speedup vs baseline: 1.1393x; 1.1393x over previous
//
#include <hip/hip_runtime.h>
#include <hip/hip_bf16.h>

#define B_ 8
#define S_ 2048
#define H_ 256
#define Z_ 64
#define CHK 32            // k per staged chunk (k2)
#define NQCH 16           // chunks per 512-k quarter (k2)
#define BS (B_*S_)        // 16384 rows

typedef short bf16x8 __attribute__((ext_vector_type(8)));
typedef float f32x4 __attribute__((ext_vector_type(4)));

__device__ __forceinline__ unsigned short f2bf(float f) {
  __hip_bfloat16 h = __float2bfloat16(f);
  return *reinterpret_cast<unsigned short*>(&h);
}
__device__ __forceinline__ float bf2f(unsigned short u) {
  __hip_bfloat16 h;
  *reinterpret_cast<unsigned short*>(&h) = u;
  return __bfloat162float(h);
}
__device__ __forceinline__ unsigned int pack2(float a, float b) {
  return (unsigned int)f2bf(a) | ((unsigned int)f2bf(b) << 16);
}

// async global->LDS DMA, 16 B/lane
__device__ __forceinline__ void gl_lds16(const void* g, void* l) {
  __builtin_amdgcn_global_load_lds(
      (const __attribute__((address_space(1))) unsigned int*)(uintptr_t)g,
      (__attribute__((address_space(3))) unsigned int*)(uintptr_t)l,
      16, 0, 0);
}

// ---------------------------------------------------------------------------
// k0: per-batch encoder-part projections
__global__ __launch_bounds__(256) void k0_base(
    const float* __restrict__ enc, const float* __restrict__ Wq,
    const float* __restrict__ Wk, const float* __restrict__ Wv,
    float* __restrict__ q0, float* __restrict__ k0, float* __restrict__ v0) {
  int b = blockIdx.x;
  int h = threadIdx.x;
  __shared__ float encs[H_];
  encs[h] = enc[b*H_ + h] + enc[B_*H_ + b*H_ + h];
  __syncthreads();
  float aq = 0.f, ak = 0.f, av = 0.f;
  #pragma unroll 4
  for (int d = 0; d < H_; d++) {
    float e = encs[d];
    aq = fmaf(e, Wq[d*H_ + h], aq);
    ak = fmaf(e, Wk[d*H_ + h], ak);
    av = fmaf(e, Wv[d*H_ + h], av);
  }
  q0[b*H_ + h] = aq;
  k0[b*H_ + h] = ak;
  v0[b*H_ + h] = av;
}

// ---------------------------------------------------------------------------
// k1: z-part projection + hi/lo bf16 split for Q,K; V -> bf16 transposed Vt
__global__ __launch_bounds__(256) void k1_prep(
    const float* __restrict__ z, const float* __restrict__ Wq,
    const float* __restrict__ Wk, const float* __restrict__ Wv,
    const float* __restrict__ q0, const float* __restrict__ k0b, const float* __restrict__ v0,
    unsigned short* __restrict__ Qhi, unsigned short* __restrict__ Qlo,
    unsigned short* __restrict__ Khi, unsigned short* __restrict__ Klo,
    unsigned short* __restrict__ Vt) {
  int b  = blockIdx.x >> 7;
  int st = blockIdx.x & 127;
  int tid = threadIdx.x;      // tid = h
  __shared__ float zs[16*Z_];
  __shared__ float vbuf[16][H_];
  {
    const float4* zp = reinterpret_cast<const float4*>(z + ((size_t)b*S_ + st*16)*Z_);
    reinterpret_cast<float4*>(zs)[tid] = zp[tid];
  }
  __syncthreads();
  float bq = q0[b*H_ + tid], bk = k0b[b*H_ + tid], bv = v0[b*H_ + tid];
  float accq[16], acck[16], accv[16];
  #pragma unroll
  for (int s = 0; s < 16; s++) { accq[s] = bq; acck[s] = bk; accv[s] = bv; }
  #pragma unroll 2
  for (int z0 = 0; z0 < Z_; z0 += 8) {
    float wq[8], wk[8], wv[8];
    #pragma unroll
    for (int j = 0; j < 8; j++) {
      wq[j] = Wq[(H_+z0+j)*H_ + tid];
      wk[j] = Wk[(H_+z0+j)*H_ + tid];
      wv[j] = Wv[(H_+z0+j)*H_ + tid];
    }
    #pragma unroll
    for (int j = 0; j < 8; j++) {
      #pragma unroll
      for (int s = 0; s < 16; s++) {
        float zz = zs[s*Z_ + z0 + j];
        accq[s] = fmaf(zz, wq[j], accq[s]);
        acck[s] = fmaf(zz, wk[j], acck[s]);
        accv[s] = fmaf(zz, wv[j], accv[s]);
      }
    }
  }
  #pragma unroll
  for (int s = 0; s < 16; s++) {
    size_t row = ((size_t)b*S_ + st*16 + s)*H_ + tid;
    unsigned short qh = f2bf(accq[s]);
    Qhi[row] = qh;
    Qlo[row] = f2bf(accq[s] - bf2f(qh));
    unsigned short kh = f2bf(acck[s]);
    Khi[row] = kh;
    Klo[row] = f2bf(acck[s] - bf2f(kh));
    vbuf[s][tid] = accv[s];
  }
  __syncthreads();
  unsigned int pk[8];
  #pragma unroll
  for (int j = 0; j < 8; j++)
    pk[j] = pack2(vbuf[2*j][tid], vbuf[2*j+1][tid]);
  uint4* vt4 = reinterpret_cast<uint4*>(Vt + ((size_t)b*H_ + tid)*S_ + st*16);
  vt4[0] = make_uint4(pk[0], pk[1], pk[2], pk[3]);
  vt4[1] = make_uint4(pk[4], pk[5], pk[6], pk[7]);
}

// ---------------------------------------------------------------------------
// k2: PURE QK^T + raw-score store + lane-local running max. No AV, no acc_o,
// no exp -> ~200 VGPRs -> 2 blocks/CU with 32 q rows/wave (K reads amortized
// over 2 q-tiles). K double-buffered via async DMA, 1 barrier/chunk. Swizzle
// phys_slot = logical ^ ((row&15)<<1): fragment reads exactly 2-way (free).
__global__ __launch_bounds__(256, 2) void k2_flash(
    const unsigned short* __restrict__ Qhi, const unsigned short* __restrict__ Qlo,
    const unsigned short* __restrict__ Khi, const unsigned short* __restrict__ Klo,
    const int* __restrict__ mask,
    float* __restrict__ attn, float* __restrict__ Mq) {
  int bb    = blockIdx.x;
  int b     = bb & 7;           // batch = XCD (L2 locality)
  int strip = (bb >> 3) & 15;   // 16 strips of 128 q
  int kq    = bb >> 7;          // k-quarter 0..3
  int qb    = strip*128;
  int k0q   = kq*512;
  int tid  = threadIdx.x;
  int wave = tid >> 6;
  int lane = tid & 63;
  int l15  = lane & 15;
  int quad = lane >> 4;
  int qw   = qb + wave*32;      // this wave's 32-row q base

  __shared__ __align__(16) unsigned short KhiL[2][32*256];   // 32 KB
  __shared__ __align__(16) unsigned short KloL[2][32*256];   // 32 KB
  // 64 KB -> 2 blocks/CU

  const unsigned short* KhiB = Khi + (size_t)b*S_*H_;
  const unsigned short* KloB = Klo + (size_t)b*S_*H_;

  int sub = lane >> 5;          // K-DMA: row pair within instr
  int c5  = lane & 31;          // K-DMA: physical 16B slot within 512B row

  auto dma_chunk = [&](int c) {
    int buf = c & 1;
    int kc = k0q + c*CHK;
    #pragma unroll
    for (int t = 0; t < 4; t++) {
      int i = wave*4 + t;                 // 16 x 1KB instrs over 4 waves
      int row = i*2 + sub;                // K row 0..31
      int lslot = c5 ^ ((row & 15) << 1); // data for physical slot c5
      size_t gs = (size_t)(kc + row)*H_ + lslot*8;
      gl_lds16(KhiB + gs, &KhiL[buf][i*512]);
      gl_lds16(KloB + gs, &KloL[buf][i*512]);
    }
  };

  // Q fragments for 2 q-tiles: A[m=l15][k=quad*8+j]
  bf16x8 qh[2][8], ql[2][8];
  #pragma unroll
  for (int qt = 0; qt < 2; qt++) {
    const unsigned short* qhp = Qhi + ((size_t)b*S_ + qw + qt*16 + l15)*H_ + quad*8;
    const unsigned short* qlp = Qlo + ((size_t)b*S_ + qw + qt*16 + l15)*H_ + quad*8;
    #pragma unroll
    for (int dc = 0; dc < 8; dc++) {
      qh[qt][dc] = *reinterpret_cast<const bf16x8*>(qhp + dc*32);
      ql[qt][dc] = *reinterpret_cast<const bf16x8*>(qlp + dc*32);
    }
  }
  int mrow[2][4];
  #pragma unroll
  for (int qt = 0; qt < 2; qt++)
    #pragma unroll
    for (int r = 0; r < 4; r++) mrow[qt][r] = mask[b*S_ + qw + qt*16 + quad*4 + r];

  float m_run[2][4] = {{-1e30f,-1e30f,-1e30f,-1e30f},{-1e30f,-1e30f,-1e30f,-1e30f}};

  dma_chunk(0);
  __syncthreads();

  for (int c = 0; c < NQCH; c++) {
    if (c+1 < NQCH) dma_chunk(c+1);     // other buffer; lands during compute
    int buf = c & 1;
    int kc  = k0q + c*CHK;
    f32x4 sacc[2][2];
    #pragma unroll
    for (int kt = 0; kt < 2; kt++) {
      int row = kt*16 + l15;
      int sw  = (row & 15) << 1;
      const unsigned short* khb = &KhiL[buf][row*256];
      const unsigned short* klb = &KloL[buf][row*256];
      f32x4 a0[2], a1[2];
      #pragma unroll
      for (int qt = 0; qt < 2; qt++) {
        a0[qt] = (f32x4){0.f,0.f,0.f,0.f};
        a1[qt] = (f32x4){0.f,0.f,0.f,0.f};
      }
      #pragma unroll
      for (int dc = 0; dc < 8; dc += 2) {
        int s0 = ((dc*4 + quad) ^ sw) * 8;
        int s1 = (((dc+1)*4 + quad) ^ sw) * 8;
        bf16x8 kh0 = *reinterpret_cast<const bf16x8*>(khb + s0);
        bf16x8 kl0 = *reinterpret_cast<const bf16x8*>(klb + s0);
        bf16x8 kh1 = *reinterpret_cast<const bf16x8*>(khb + s1);
        bf16x8 kl1 = *reinterpret_cast<const bf16x8*>(klb + s1);
        #pragma unroll
        for (int qt = 0; qt < 2; qt++) {   // each K frag feeds both q-tiles
          a0[qt] = __builtin_amdgcn_mfma_f32_16x16x32_bf16(qh[qt][dc],   kh0, a0[qt], 0, 0, 0);
          a1[qt] = __builtin_amdgcn_mfma_f32_16x16x32_bf16(qh[qt][dc+1], kh1, a1[qt], 0, 0, 0);
          a0[qt] = __builtin_amdgcn_mfma_f32_16x16x32_bf16(ql[qt][dc],   kh0, a0[qt], 0, 0, 0);
          a1[qt] = __builtin_amdgcn_mfma_f32_16x16x32_bf16(ql[qt][dc+1], kh1, a1[qt], 0, 0, 0);
          a0[qt] = __builtin_amdgcn_mfma_f32_16x16x32_bf16(qh[qt][dc],   kl0, a0[qt], 0, 0, 0);
          a1[qt] = __builtin_amdgcn_mfma_f32_16x16x32_bf16(qh[qt][dc+1], kl1, a1[qt], 0, 0, 0);
        }
      }
      #pragma unroll
      for (int qt = 0; qt < 2; qt++) sacc[qt][kt] = a0[qt] + a1[qt];
    }
    // masked raw scores out; lane-local max only (cross-lane reduce deferred)
    #pragma unroll
    for (int qt = 0; qt < 2; qt++) {
      #pragma unroll
      for (int r = 0; r < 4; r++) {
        float se0 = mrow[qt][r] ? sacc[qt][0][r]*0.0625f : -1e9f;
        float se1 = mrow[qt][r] ? sacc[qt][1][r]*0.0625f : -1e9f;
        m_run[qt][r] = fmaxf(m_run[qt][r], fmaxf(se0, se1));
        size_t rb = ((size_t)b*S_ + qw + qt*16 + quad*4 + r)*S_ + kc;
        attn[rb + l15]      = se0;
        attn[rb + 16 + l15] = se1;
      }
    }
    __syncthreads();   // readers done + DMA(c+1) drained
  }

  // tail: cross-lane max reduce (once), write per-quarter row max
  #pragma unroll
  for (int qt = 0; qt < 2; qt++) {
    #pragma unroll
    for (int r = 0; r < 4; r++) {
      float m = m_run[qt][r];
      m = fmaxf(m, __shfl_xor(m, 1));
      m = fmaxf(m, __shfl_xor(m, 2));
      m = fmaxf(m, __shfl_xor(m, 4));
      m = fmaxf(m, __shfl_xor(m, 8));
      if (l15 == 0)
        Mq[kq*BS + b*S_ + qw + qt*16 + quad*4 + r] = m;
    }
  }
}

// ---------------------------------------------------------------------------
// k3a: fused exp + AV + l. m is FIXED (from Mq) -> no online rescale. Scores
// read directly in MFMA-A layout (lane l15 = q-row, quad = col group), so the
// P fragments are built in-register: no transpose, no P LDS. V staged in
// swizzled LDS (2-way reads). Writes out, Mfin, Lfin (attn normalized by k3b).
__global__ __launch_bounds__(256) void k3a(
    const float* __restrict__ attn, const unsigned short* __restrict__ Vt,
    const float* __restrict__ Mq, float* __restrict__ outp,
    float* __restrict__ Mfin, float* __restrict__ Lfin) {
  int bb = blockIdx.x;            // grid 256 = 8 b x 32 strips of 64 q
  int b  = bb & 7;
  int qb = (bb >> 3) * 64;
  int tid  = threadIdx.x;
  int wave = tid >> 6;
  int lane = tid & 63;
  int l15  = lane & 15;
  int quad = lane >> 4;
  int qw   = qb + wave*16;

  __shared__ __align__(16) unsigned short VtL[2][256*64];   // 2 x 32 KB
  __shared__ float lred[4][16];

  const unsigned short* VtB = Vt + (size_t)b*H_*S_;
  int gr = b*S_ + qw + l15;       // this lane's q-row
  float m = fmaxf(fmaxf(Mq[gr], Mq[BS + gr]), fmaxf(Mq[2*BS + gr], Mq[3*BS + gr]));

  int hsub = lane >> 3;           // V-DMA: h row within 8
  int slot = lane & 7;            // V-DMA: physical 16B slot within 128B row

  auto dma_v = [&](int c) {       // 64-k chunk -> 32 KB
    int buf = c & 1;
    int kc = c*64;
    #pragma unroll
    for (int t = 0; t < 8; t++) {
      int i = wave*8 + t;         // 32 x 1KB instrs over 4 waves
      int h = i*8 + hsub;
      int lslot = slot ^ (((h >> 2) & 3) << 1);
      gl_lds16(VtB + (size_t)h*S_ + kc + lslot*8, &VtL[buf][i*512]);
    }
  };

  f32x4 acc[16];
  #pragma unroll
  for (int ht = 0; ht < 16; ht++) acc[ht] = (f32x4){0.f, 0.f, 0.f, 0.f};
  float lpart = 0.f;

  const float* sp = attn + (size_t)gr*S_ + quad*8;
  dma_v(0);
  float4 s0 = *reinterpret_cast<const float4*>(sp);
  float4 s1 = *reinterpret_cast<const float4*>(sp + 4);
  float4 s2 = *reinterpret_cast<const float4*>(sp + 32);
  float4 s3 = *reinterpret_cast<const float4*>(sp + 36);
  __syncthreads();

  for (int c = 0; c < 32; c++) {
    if (c+1 < 32) dma_v(c+1);
    int buf = c & 1;
    // prefetch next chunk's scores while processing current
    float4 n0, n1, n2, n3;
    if (c+1 < 32) {
      const float* np = sp + (c+1)*64;
      n0 = *reinterpret_cast<const float4*>(np);
      n1 = *reinterpret_cast<const float4*>(np + 4);
      n2 = *reinterpret_cast<const float4*>(np + 32);
      n3 = *reinterpret_cast<const float4*>(np + 36);
    }
    // exp (m fixed) + l partial + build P A-frags in-register
    float p0 = __expf(s0.x - m), p1 = __expf(s0.y - m);
    float p2 = __expf(s0.z - m), p3 = __expf(s0.w - m);
    float p4 = __expf(s1.x - m), p5 = __expf(s1.y - m);
    float p6 = __expf(s1.z - m), p7 = __expf(s1.w - m);
    float q0f = __expf(s2.x - m), q1f = __expf(s2.y - m);
    float q2f = __expf(s2.z - m), q3f = __expf(s2.w - m);
    float q4f = __expf(s3.x - m), q5f = __expf(s3.y - m);
    float q6f = __expf(s3.z - m), q7f = __expf(s3.w - m);
    lpart += p0+p1+p2+p3+p4+p5+p6+p7+q0f+q1f+q2f+q3f+q4f+q5f+q6f+q7f;
    unsigned int pw[4] = {pack2(p0,p1), pack2(p2,p3), pack2(p4,p5), pack2(p6,p7)};
    unsigned int qv[4] = {pack2(q0f,q1f), pack2(q2f,q3f), pack2(q4f,q5f), pack2(q6f,q7f)};
    bf16x8 pa0, pa1;
    memcpy(&pa0, pw, 16);
    memcpy(&pa1, qv, 16);
    // AV: V B-frags from swizzled LDS
    int swz = ((l15 >> 2) & 3) << 1;
    #pragma unroll
    for (int ht = 0; ht < 16; ht++) {
      const unsigned short* vb = &VtL[buf][(ht*16 + l15)*64];
      bf16x8 v0 = *reinterpret_cast<const bf16x8*>(vb + (quad ^ swz)*8);
      bf16x8 v1 = *reinterpret_cast<const bf16x8*>(vb + ((4 + quad) ^ swz)*8);
      acc[ht] = __builtin_amdgcn_mfma_f32_16x16x32_bf16(pa0, v0, acc[ht], 0, 0, 0);
      acc[ht] = __builtin_amdgcn_mfma_f32_16x16x32_bf16(pa1, v1, acc[ht], 0, 0, 0);
    }
    s0 = n0; s1 = n1; s2 = n2; s3 = n3;
    __syncthreads();
  }

  // l: reduce across quad (row = l15)
  lpart += __shfl_xor(lpart, 16);
  lpart += __shfl_xor(lpart, 32);
  if (quad == 0) {
    lred[wave][l15] = lpart;
    Lfin[gr] = lpart;
    Mfin[gr] = m;
  }
  // out (C/D rows = quad*4+r): il via wave-private LDS
  float il[4];
  #pragma unroll
  for (int r = 0; r < 4; r++) il[r] = 1.f / lred[wave][quad*4 + r];
  #pragma unroll
  for (int ht = 0; ht < 16; ht++)
    #pragma unroll
    for (int r = 0; r < 4; r++)
      outp[((size_t)b*S_ + qw + quad*4 + r)*H_ + ht*16 + l15] = acc[ht][r] * il[r];
}

// ---------------------------------------------------------------------------
// k3b: attn[row][k] = exp(se - Mfin[row]) / Lfin[row]  (in-place, L3-fed)
__global__ __launch_bounds__(256) void k3b(
    float* __restrict__ attn, const float* __restrict__ Mfin,
    const float* __restrict__ Lfin) {
  int gr  = blockIdx.x;
  int tid = threadIdx.x;
  float m  = Mfin[gr];
  float il = 1.f / Lfin[gr];
  float4* pa = reinterpret_cast<float4*>(attn + (size_t)gr*S_ + tid*8);
  float4 x0 = pa[0], x1 = pa[1];
  x0.x = __expf(x0.x - m)*il; x0.y = __expf(x0.y - m)*il;
  x0.z = __expf(x0.z - m)*il; x0.w = __expf(x0.w - m)*il;
  x1.x = __expf(x1.x - m)*il; x1.y = __expf(x1.y - m)*il;
  x1.z = __expf(x1.z - m)*il; x1.w = __expf(x1.w - m)*il;
  pa[0] = x0; pa[1] = x1;
}

// ---------------------------------------------------------------------------
extern "C" void kernel_launch(void* const* d_in, const int* in_sizes, int n_in,
                              void* d_out, int out_size, void* d_ws, size_t ws_size,
                              hipStream_t stream) {
  const float* enc = (const float*)d_in[0];
  // d_in[1] = decoder_hidden_state: unused by the reference
  const float* z   = (const float*)d_in[2];
  const int* mask  = (const int*)d_in[3];
  const float* Wq  = (const float*)d_in[4];
  const float* Wk  = (const float*)d_in[5];
  const float* Wv  = (const float*)d_in[6];

  char* ws = (char*)d_ws;
  const size_t MB = 1024*1024;
  unsigned short* Qhi = (unsigned short*)(ws);
  unsigned short* Qlo = (unsigned short*)(ws +  8*MB);
  unsigned short* Khi = (unsigned short*)(ws + 16*MB);
  unsigned short* Klo = (unsigned short*)(ws + 24*MB);
  unsigned short* Vt  = (unsigned short*)(ws + 32*MB);
  float* q0 = (float*)(ws + 40*MB);
  float* k0 = q0 + B_*H_;
  float* v0 = k0 + B_*H_;
  float* Mq   = (float*)(ws + 41*MB);                 // [4][B*S] = 256 KB
  float* Mfin = (float*)(ws + 41*MB + 512*1024);      // [B*S]
  float* Lfin = (float*)(ws + 41*MB + 512*1024 + 64*1024);

  float* outp = (float*)d_out;
  float* attn = outp + (size_t)B_*S_*H_;

  k0_base<<<B_, 256, 0, stream>>>(enc, Wq, Wk, Wv, q0, k0, v0);
  k1_prep<<<B_*(S_/16), 256, 0, stream>>>(z, Wq, Wk, Wv, q0, k0, v0,
                                          Qhi, Qlo, Khi, Klo, Vt);
  k2_flash<<<B_*(S_/128)*4, 256, 0, stream>>>(Qhi, Qlo, Khi, Klo, mask,
                                              attn, Mq);
  k3a<<<B_*(S_/64), 256, 0, stream>>>(attn, Vt, Mq, outp, Mfin, Lfin);
  k3b<<<B_*S_, 256, 0, stream>>>(attn, Mfin, Lfin);
}

// Round 12
// 337.879 us; speedup vs baseline: 1.1397x; 1.0003x over previous
//
#include <hip/hip_runtime.h>
#include <hip/hip_bf16.h>

#define B_ 8
#define S_ 2048
#define H_ 256
#define Z_ 64
#define CHK 32            // k per staged chunk (k2)
#define NQCH 16           // chunks per 512-k quarter (k2)
#define BS (B_*S_)        // 16384 rows

typedef short bf16x8 __attribute__((ext_vector_type(8)));
typedef float f32x4 __attribute__((ext_vector_type(4)));

__device__ __forceinline__ unsigned short f2bf(float f) {
  __hip_bfloat16 h = __float2bfloat16(f);
  return *reinterpret_cast<unsigned short*>(&h);
}
__device__ __forceinline__ float bf2f(unsigned short u) {
  __hip_bfloat16 h;
  *reinterpret_cast<unsigned short*>(&h) = u;
  return __bfloat162float(h);
}
__device__ __forceinline__ unsigned int pack2(float a, float b) {
  return (unsigned int)f2bf(a) | ((unsigned int)f2bf(b) << 16);
}

// async global->LDS DMA, 16 B/lane
__device__ __forceinline__ void gl_lds16(const void* g, void* l) {
  __builtin_amdgcn_global_load_lds(
      (const __attribute__((address_space(1))) unsigned int*)(uintptr_t)g,
      (__attribute__((address_space(3))) unsigned int*)(uintptr_t)l,
      16, 0, 0);
}

// ---------------------------------------------------------------------------
// k0: per-batch encoder-part projections
__global__ __launch_bounds__(256) void k0_base(
    const float* __restrict__ enc, const float* __restrict__ Wq,
    const float* __restrict__ Wk, const float* __restrict__ Wv,
    float* __restrict__ q0, float* __restrict__ k0, float* __restrict__ v0) {
  int b = blockIdx.x;
  int h = threadIdx.x;
  __shared__ float encs[H_];
  encs[h] = enc[b*H_ + h] + enc[B_*H_ + b*H_ + h];
  __syncthreads();
  float aq = 0.f, ak = 0.f, av = 0.f;
  #pragma unroll 4
  for (int d = 0; d < H_; d++) {
    float e = encs[d];
    aq = fmaf(e, Wq[d*H_ + h], aq);
    ak = fmaf(e, Wk[d*H_ + h], ak);
    av = fmaf(e, Wv[d*H_ + h], av);
  }
  q0[b*H_ + h] = aq;
  k0[b*H_ + h] = ak;
  v0[b*H_ + h] = av;
}

// ---------------------------------------------------------------------------
// k1: z-part projection + hi/lo bf16 split for Q,K; V -> bf16 transposed Vt
__global__ __launch_bounds__(256) void k1_prep(
    const float* __restrict__ z, const float* __restrict__ Wq,
    const float* __restrict__ Wk, const float* __restrict__ Wv,
    const float* __restrict__ q0, const float* __restrict__ k0b, const float* __restrict__ v0,
    unsigned short* __restrict__ Qhi, unsigned short* __restrict__ Qlo,
    unsigned short* __restrict__ Khi, unsigned short* __restrict__ Klo,
    unsigned short* __restrict__ Vt) {
  int b  = blockIdx.x >> 7;
  int st = blockIdx.x & 127;
  int tid = threadIdx.x;      // tid = h
  __shared__ float zs[16*Z_];
  __shared__ float vbuf[16][H_];
  {
    const float4* zp = reinterpret_cast<const float4*>(z + ((size_t)b*S_ + st*16)*Z_);
    reinterpret_cast<float4*>(zs)[tid] = zp[tid];
  }
  __syncthreads();
  float bq = q0[b*H_ + tid], bk = k0b[b*H_ + tid], bv = v0[b*H_ + tid];
  float accq[16], acck[16], accv[16];
  #pragma unroll
  for (int s = 0; s < 16; s++) { accq[s] = bq; acck[s] = bk; accv[s] = bv; }
  #pragma unroll 2
  for (int z0 = 0; z0 < Z_; z0 += 8) {
    float wq[8], wk[8], wv[8];
    #pragma unroll
    for (int j = 0; j < 8; j++) {
      wq[j] = Wq[(H_+z0+j)*H_ + tid];
      wk[j] = Wk[(H_+z0+j)*H_ + tid];
      wv[j] = Wv[(H_+z0+j)*H_ + tid];
    }
    #pragma unroll
    for (int j = 0; j < 8; j++) {
      #pragma unroll
      for (int s = 0; s < 16; s++) {
        float zz = zs[s*Z_ + z0 + j];
        accq[s] = fmaf(zz, wq[j], accq[s]);
        acck[s] = fmaf(zz, wk[j], acck[s]);
        accv[s] = fmaf(zz, wv[j], accv[s]);
      }
    }
  }
  #pragma unroll
  for (int s = 0; s < 16; s++) {
    size_t row = ((size_t)b*S_ + st*16 + s)*H_ + tid;
    unsigned short qh = f2bf(accq[s]);
    Qhi[row] = qh;
    Qlo[row] = f2bf(accq[s] - bf2f(qh));
    unsigned short kh = f2bf(acck[s]);
    Khi[row] = kh;
    Klo[row] = f2bf(acck[s] - bf2f(kh));
    vbuf[s][tid] = accv[s];
  }
  __syncthreads();
  unsigned int pk[8];
  #pragma unroll
  for (int j = 0; j < 8; j++)
    pk[j] = pack2(vbuf[2*j][tid], vbuf[2*j+1][tid]);
  uint4* vt4 = reinterpret_cast<uint4*>(Vt + ((size_t)b*H_ + tid)*S_ + st*16);
  vt4[0] = make_uint4(pk[0], pk[1], pk[2], pk[3]);
  vt4[1] = make_uint4(pk[4], pk[5], pk[6], pk[7]);
}

// ---------------------------------------------------------------------------
// k2: QK^T + raw-score store + online (m,l) per row (scalar state only — no
// O accumulator, no P, no AV). 32 q rows/wave, 2 blocks/CU. K double-buffered
// via async DMA, 1 barrier/chunk, 2-way-free XOR swizzle.
__global__ __launch_bounds__(256, 2) void k2_flash(
    const unsigned short* __restrict__ Qhi, const unsigned short* __restrict__ Qlo,
    const unsigned short* __restrict__ Khi, const unsigned short* __restrict__ Klo,
    const int* __restrict__ mask,
    float* __restrict__ attn, float* __restrict__ Mq, float* __restrict__ Lq) {
  int bb    = blockIdx.x;
  int b     = bb & 7;           // batch = XCD (L2 locality)
  int strip = (bb >> 3) & 15;   // 16 strips of 128 q
  int kq    = bb >> 7;          // k-quarter 0..3
  int qb    = strip*128;
  int k0q   = kq*512;
  int tid  = threadIdx.x;
  int wave = tid >> 6;
  int lane = tid & 63;
  int l15  = lane & 15;
  int quad = lane >> 4;
  int qw   = qb + wave*32;      // this wave's 32-row q base

  __shared__ __align__(16) unsigned short KhiL[2][32*256];   // 32 KB
  __shared__ __align__(16) unsigned short KloL[2][32*256];   // 32 KB

  const unsigned short* KhiB = Khi + (size_t)b*S_*H_;
  const unsigned short* KloB = Klo + (size_t)b*S_*H_;

  int sub = lane >> 5;          // K-DMA: row pair within instr
  int c5  = lane & 31;          // K-DMA: physical 16B slot within 512B row

  auto dma_chunk = [&](int c) {
    int buf = c & 1;
    int kc = k0q + c*CHK;
    #pragma unroll
    for (int t = 0; t < 4; t++) {
      int i = wave*4 + t;                 // 16 x 1KB instrs over 4 waves
      int row = i*2 + sub;                // K row 0..31
      int lslot = c5 ^ ((row & 15) << 1); // data for physical slot c5
      size_t gs = (size_t)(kc + row)*H_ + lslot*8;
      gl_lds16(KhiB + gs, &KhiL[buf][i*512]);
      gl_lds16(KloB + gs, &KloL[buf][i*512]);
    }
  };

  // Q fragments for 2 q-tiles: A[m=l15][k=quad*8+j]
  bf16x8 qh[2][8], ql[2][8];
  #pragma unroll
  for (int qt = 0; qt < 2; qt++) {
    const unsigned short* qhp = Qhi + ((size_t)b*S_ + qw + qt*16 + l15)*H_ + quad*8;
    const unsigned short* qlp = Qlo + ((size_t)b*S_ + qw + qt*16 + l15)*H_ + quad*8;
    #pragma unroll
    for (int dc = 0; dc < 8; dc++) {
      qh[qt][dc] = *reinterpret_cast<const bf16x8*>(qhp + dc*32);
      ql[qt][dc] = *reinterpret_cast<const bf16x8*>(qlp + dc*32);
    }
  }
  int mrow[2][4];
  #pragma unroll
  for (int qt = 0; qt < 2; qt++)
    #pragma unroll
    for (int r = 0; r < 4; r++) mrow[qt][r] = mask[b*S_ + qw + qt*16 + quad*4 + r];

  float m_run[2][4] = {{-1e30f,-1e30f,-1e30f,-1e30f},{-1e30f,-1e30f,-1e30f,-1e30f}};
  float l_run[2][4] = {{0.f,0.f,0.f,0.f},{0.f,0.f,0.f,0.f}};

  dma_chunk(0);
  __syncthreads();

  for (int c = 0; c < NQCH; c++) {
    if (c+1 < NQCH) dma_chunk(c+1);     // other buffer; lands during compute
    int buf = c & 1;
    int kc  = k0q + c*CHK;
    f32x4 sacc[2][2];
    #pragma unroll
    for (int kt = 0; kt < 2; kt++) {
      int row = kt*16 + l15;
      int sw  = (row & 15) << 1;
      const unsigned short* khb = &KhiL[buf][row*256];
      const unsigned short* klb = &KloL[buf][row*256];
      f32x4 a0[2], a1[2];
      #pragma unroll
      for (int qt = 0; qt < 2; qt++) {
        a0[qt] = (f32x4){0.f,0.f,0.f,0.f};
        a1[qt] = (f32x4){0.f,0.f,0.f,0.f};
      }
      #pragma unroll
      for (int dc = 0; dc < 8; dc += 2) {
        int s0 = ((dc*4 + quad) ^ sw) * 8;
        int s1 = (((dc+1)*4 + quad) ^ sw) * 8;
        bf16x8 kh0 = *reinterpret_cast<const bf16x8*>(khb + s0);
        bf16x8 kl0 = *reinterpret_cast<const bf16x8*>(klb + s0);
        bf16x8 kh1 = *reinterpret_cast<const bf16x8*>(khb + s1);
        bf16x8 kl1 = *reinterpret_cast<const bf16x8*>(klb + s1);
        #pragma unroll
        for (int qt = 0; qt < 2; qt++) {   // each K frag feeds both q-tiles
          a0[qt] = __builtin_amdgcn_mfma_f32_16x16x32_bf16(qh[qt][dc],   kh0, a0[qt], 0, 0, 0);
          a1[qt] = __builtin_amdgcn_mfma_f32_16x16x32_bf16(qh[qt][dc+1], kh1, a1[qt], 0, 0, 0);
          a0[qt] = __builtin_amdgcn_mfma_f32_16x16x32_bf16(ql[qt][dc],   kh0, a0[qt], 0, 0, 0);
          a1[qt] = __builtin_amdgcn_mfma_f32_16x16x32_bf16(ql[qt][dc+1], kh1, a1[qt], 0, 0, 0);
          a0[qt] = __builtin_amdgcn_mfma_f32_16x16x32_bf16(qh[qt][dc],   kl0, a0[qt], 0, 0, 0);
          a1[qt] = __builtin_amdgcn_mfma_f32_16x16x32_bf16(qh[qt][dc+1], kl1, a1[qt], 0, 0, 0);
        }
      }
      #pragma unroll
      for (int qt = 0; qt < 2; qt++) sacc[qt][kt] = a0[qt] + a1[qt];
    }
    // raw scores out + online (m,l) scalar update (state uniform across l15)
    #pragma unroll
    for (int qt = 0; qt < 2; qt++) {
      #pragma unroll
      for (int r = 0; r < 4; r++) {
        float se0 = mrow[qt][r] ? sacc[qt][0][r]*0.0625f : -1e9f;
        float se1 = mrow[qt][r] ? sacc[qt][1][r]*0.0625f : -1e9f;
        size_t rb = ((size_t)b*S_ + qw + qt*16 + quad*4 + r)*S_ + kc;
        attn[rb + l15]      = se0;
        attn[rb + 16 + l15] = se1;
        float ml = fmaxf(se0, se1);
        ml = fmaxf(ml, __shfl_xor(ml, 1));
        ml = fmaxf(ml, __shfl_xor(ml, 2));
        ml = fmaxf(ml, __shfl_xor(ml, 4));
        ml = fmaxf(ml, __shfl_xor(ml, 8));
        float mnew = fmaxf(m_run[qt][r], ml);
        float alpha = __expf(m_run[qt][r] - mnew);
        float ls = __expf(se0 - mnew) + __expf(se1 - mnew);
        ls += __shfl_xor(ls, 1);
        ls += __shfl_xor(ls, 2);
        ls += __shfl_xor(ls, 4);
        ls += __shfl_xor(ls, 8);
        l_run[qt][r] = l_run[qt][r]*alpha + ls;
        m_run[qt][r] = mnew;
      }
    }
    __syncthreads();   // readers done + DMA(c+1) drained
  }

  // tail: (m,l) are already lane-uniform; one lane writes per row
  if (l15 == 0) {
    #pragma unroll
    for (int qt = 0; qt < 2; qt++)
      #pragma unroll
      for (int r = 0; r < 4; r++) {
        int idx = kq*BS + b*S_ + qw + qt*16 + quad*4 + r;
        Mq[idx] = m_run[qt][r];
        Lq[idx] = l_run[qt][r];
      }
  }
}

// ---------------------------------------------------------------------------
// k3a: final fused pass. (m, il) known upfront from Mq/Lq -> single sweep:
// p*il = exp(se-m)*il is written as the FINAL attn (fp32) and packed (already
// normalized) into bf16 P fragments, so AV produces out directly. No second
// pass, no k3b, no lred.
__global__ __launch_bounds__(256) void k3a(
    float* __restrict__ attn, const unsigned short* __restrict__ Vt,
    const float* __restrict__ Mq, const float* __restrict__ Lq,
    float* __restrict__ outp) {
  int bb = blockIdx.x;            // grid 256 = 8 b x 32 strips of 64 q
  int b  = bb & 7;
  int qb = (bb >> 3) * 64;
  int tid  = threadIdx.x;
  int wave = tid >> 6;
  int lane = tid & 63;
  int l15  = lane & 15;
  int quad = lane >> 4;
  int qw   = qb + wave*16;

  __shared__ __align__(16) unsigned short VtL[2][256*64];   // 2 x 32 KB

  const unsigned short* VtB = Vt + (size_t)b*H_*S_;
  int gr = b*S_ + qw + l15;       // this lane's q-row
  float m0 = Mq[gr], m1 = Mq[BS+gr], m2 = Mq[2*BS+gr], m3 = Mq[3*BS+gr];
  float m = fmaxf(fmaxf(m0, m1), fmaxf(m2, m3));
  float l = Lq[gr]*__expf(m0-m) + Lq[BS+gr]*__expf(m1-m)
          + Lq[2*BS+gr]*__expf(m2-m) + Lq[3*BS+gr]*__expf(m3-m);
  float il = 1.f / l;

  int hsub = lane >> 3;           // V-DMA: h row within 8
  int slot = lane & 7;            // V-DMA: physical 16B slot within 128B row

  auto dma_v = [&](int c) {       // 64-k chunk -> 32 KB
    int buf = c & 1;
    int kc = c*64;
    #pragma unroll
    for (int t = 0; t < 8; t++) {
      int i = wave*8 + t;         // 32 x 1KB instrs over 4 waves
      int h = i*8 + hsub;
      int lslot = slot ^ (((h >> 2) & 3) << 1);
      gl_lds16(VtB + (size_t)h*S_ + kc + lslot*8, &VtL[buf][i*512]);
    }
  };

  f32x4 acc[16];
  #pragma unroll
  for (int ht = 0; ht < 16; ht++) acc[ht] = (f32x4){0.f, 0.f, 0.f, 0.f};

  float* sp = attn + (size_t)gr*S_ + quad*8;
  dma_v(0);
  float4 s0 = *reinterpret_cast<const float4*>(sp);
  float4 s1 = *reinterpret_cast<const float4*>(sp + 4);
  float4 s2 = *reinterpret_cast<const float4*>(sp + 32);
  float4 s3 = *reinterpret_cast<const float4*>(sp + 36);
  __syncthreads();

  for (int c = 0; c < 32; c++) {
    if (c+1 < 32) dma_v(c+1);
    int buf = c & 1;
    // prefetch next chunk's scores while processing current
    float4 n0, n1, n2, n3;
    if (c+1 < 32) {
      const float* np = sp + (c+1)*64;
      n0 = *reinterpret_cast<const float4*>(np);
      n1 = *reinterpret_cast<const float4*>(np + 4);
      n2 = *reinterpret_cast<const float4*>(np + 32);
      n3 = *reinterpret_cast<const float4*>(np + 36);
    }
    // normalized probabilities (m, il fixed)
    float p0 = __expf(s0.x - m)*il, p1 = __expf(s0.y - m)*il;
    float p2 = __expf(s0.z - m)*il, p3 = __expf(s0.w - m)*il;
    float p4 = __expf(s1.x - m)*il, p5 = __expf(s1.y - m)*il;
    float p6 = __expf(s1.z - m)*il, p7 = __expf(s1.w - m)*il;
    float q0f = __expf(s2.x - m)*il, q1f = __expf(s2.y - m)*il;
    float q2f = __expf(s2.z - m)*il, q3f = __expf(s2.w - m)*il;
    float q4f = __expf(s3.x - m)*il, q5f = __expf(s3.y - m)*il;
    float q6f = __expf(s3.z - m)*il, q7f = __expf(s3.w - m)*il;
    // final attn values (in-place over the raw scores)
    float* ap = sp + c*64;
    *reinterpret_cast<float4*>(ap)      = make_float4(p0, p1, p2, p3);
    *reinterpret_cast<float4*>(ap + 4)  = make_float4(p4, p5, p6, p7);
    *reinterpret_cast<float4*>(ap + 32) = make_float4(q0f, q1f, q2f, q3f);
    *reinterpret_cast<float4*>(ap + 36) = make_float4(q4f, q5f, q6f, q7f);
    // P fragments (already normalized) for AV
    unsigned int pw[4] = {pack2(p0,p1), pack2(p2,p3), pack2(p4,p5), pack2(p6,p7)};
    unsigned int qv[4] = {pack2(q0f,q1f), pack2(q2f,q3f), pack2(q4f,q5f), pack2(q6f,q7f)};
    bf16x8 pa0, pa1;
    memcpy(&pa0, pw, 16);
    memcpy(&pa1, qv, 16);
    int swz = ((l15 >> 2) & 3) << 1;
    #pragma unroll
    for (int ht = 0; ht < 16; ht++) {
      const unsigned short* vb = &VtL[buf][(ht*16 + l15)*64];
      bf16x8 v0 = *reinterpret_cast<const bf16x8*>(vb + (quad ^ swz)*8);
      bf16x8 v1 = *reinterpret_cast<const bf16x8*>(vb + ((4 + quad) ^ swz)*8);
      acc[ht] = __builtin_amdgcn_mfma_f32_16x16x32_bf16(pa0, v0, acc[ht], 0, 0, 0);
      acc[ht] = __builtin_amdgcn_mfma_f32_16x16x32_bf16(pa1, v1, acc[ht], 0, 0, 0);
    }
    s0 = n0; s1 = n1; s2 = n2; s3 = n3;
    __syncthreads();
  }

  // out is already normalized (il folded into P)
  #pragma unroll
  for (int ht = 0; ht < 16; ht++)
    #pragma unroll
    for (int r = 0; r < 4; r++)
      outp[((size_t)b*S_ + qw + quad*4 + r)*H_ + ht*16 + l15] = acc[ht][r];
}

// ---------------------------------------------------------------------------
extern "C" void kernel_launch(void* const* d_in, const int* in_sizes, int n_in,
                              void* d_out, int out_size, void* d_ws, size_t ws_size,
                              hipStream_t stream) {
  const float* enc = (const float*)d_in[0];
  // d_in[1] = decoder_hidden_state: unused by the reference
  const float* z   = (const float*)d_in[2];
  const int* mask  = (const int*)d_in[3];
  const float* Wq  = (const float*)d_in[4];
  const float* Wk  = (const float*)d_in[5];
  const float* Wv  = (const float*)d_in[6];

  char* ws = (char*)d_ws;
  const size_t MB = 1024*1024;
  unsigned short* Qhi = (unsigned short*)(ws);
  unsigned short* Qlo = (unsigned short*)(ws +  8*MB);
  unsigned short* Khi = (unsigned short*)(ws + 16*MB);
  unsigned short* Klo = (unsigned short*)(ws + 24*MB);
  unsigned short* Vt  = (unsigned short*)(ws + 32*MB);
  float* q0 = (float*)(ws + 40*MB);
  float* k0 = q0 + B_*H_;
  float* v0 = k0 + B_*H_;
  float* Mq = (float*)(ws + 41*MB);                 // [4][B*S] = 256 KB
  float* Lq = (float*)(ws + 41*MB + 512*1024);      // [4][B*S] = 256 KB

  float* outp = (float*)d_out;
  float* attn = outp + (size_t)B_*S_*H_;

  k0_base<<<B_, 256, 0, stream>>>(enc, Wq, Wk, Wv, q0, k0, v0);
  k1_prep<<<B_*(S_/16), 256, 0, stream>>>(z, Wq, Wk, Wv, q0, k0, v0,
                                          Qhi, Qlo, Khi, Klo, Vt);
  k2_flash<<<B_*(S_/128)*4, 256, 0, stream>>>(Qhi, Qlo, Khi, Klo, mask,
                                              attn, Mq, Lq);
  k3a<<<B_*(S_/64), 256, 0, stream>>>(attn, Vt, Mq, Lq, outp);
}

// Round 13
// 325.132 us; speedup vs baseline: 1.1843x; 1.0392x over previous
//
#include <hip/hip_runtime.h>
#include <hip/hip_bf16.h>

#define B_ 8
#define S_ 2048
#define H_ 256
#define Z_ 64
#define CHK 32            // k per staged chunk (k2)
#define NQCH 16           // chunks per 512-k quarter (k2)
#define BS (B_*S_)        // 16384 rows

typedef short bf16x8 __attribute__((ext_vector_type(8)));
typedef float f32x4 __attribute__((ext_vector_type(4)));

__device__ __forceinline__ unsigned short f2bf(float f) {
  __hip_bfloat16 h = __float2bfloat16(f);
  return *reinterpret_cast<unsigned short*>(&h);
}
__device__ __forceinline__ float bf2f(unsigned short u) {
  __hip_bfloat16 h;
  *reinterpret_cast<unsigned short*>(&h) = u;
  return __bfloat162float(h);
}
__device__ __forceinline__ unsigned int pack2(float a, float b) {
  return (unsigned int)f2bf(a) | ((unsigned int)f2bf(b) << 16);
}

// async global->LDS DMA, 16 B/lane
__device__ __forceinline__ void gl_lds16(const void* g, void* l) {
  __builtin_amdgcn_global_load_lds(
      (const __attribute__((address_space(1))) unsigned int*)(uintptr_t)g,
      (__attribute__((address_space(3))) unsigned int*)(uintptr_t)l,
      16, 0, 0);
}

// ---------------------------------------------------------------------------
// k0: per-batch encoder-part projections
__global__ __launch_bounds__(256) void k0_base(
    const float* __restrict__ enc, const float* __restrict__ Wq,
    const float* __restrict__ Wk, const float* __restrict__ Wv,
    float* __restrict__ q0, float* __restrict__ k0, float* __restrict__ v0) {
  int b = blockIdx.x;
  int h = threadIdx.x;
  __shared__ float encs[H_];
  encs[h] = enc[b*H_ + h] + enc[B_*H_ + b*H_ + h];
  __syncthreads();
  float aq = 0.f, ak = 0.f, av = 0.f;
  #pragma unroll 4
  for (int d = 0; d < H_; d++) {
    float e = encs[d];
    aq = fmaf(e, Wq[d*H_ + h], aq);
    ak = fmaf(e, Wk[d*H_ + h], ak);
    av = fmaf(e, Wv[d*H_ + h], av);
  }
  q0[b*H_ + h] = aq;
  k0[b*H_ + h] = ak;
  v0[b*H_ + h] = av;
}

// ---------------------------------------------------------------------------
// k1: z-part projection + hi/lo bf16 split for Q,K; V -> bf16 transposed Vt
__global__ __launch_bounds__(256) void k1_prep(
    const float* __restrict__ z, const float* __restrict__ Wq,
    const float* __restrict__ Wk, const float* __restrict__ Wv,
    const float* __restrict__ q0, const float* __restrict__ k0b, const float* __restrict__ v0,
    unsigned short* __restrict__ Qhi, unsigned short* __restrict__ Qlo,
    unsigned short* __restrict__ Khi, unsigned short* __restrict__ Klo,
    unsigned short* __restrict__ Vt) {
  int b  = blockIdx.x >> 7;
  int st = blockIdx.x & 127;
  int tid = threadIdx.x;      // tid = h
  __shared__ float zs[16*Z_];
  __shared__ float vbuf[16][H_];
  {
    const float4* zp = reinterpret_cast<const float4*>(z + ((size_t)b*S_ + st*16)*Z_);
    reinterpret_cast<float4*>(zs)[tid] = zp[tid];
  }
  __syncthreads();
  float bq = q0[b*H_ + tid], bk = k0b[b*H_ + tid], bv = v0[b*H_ + tid];
  float accq[16], acck[16], accv[16];
  #pragma unroll
  for (int s = 0; s < 16; s++) { accq[s] = bq; acck[s] = bk; accv[s] = bv; }
  #pragma unroll 2
  for (int z0 = 0; z0 < Z_; z0 += 8) {
    float wq[8], wk[8], wv[8];
    #pragma unroll
    for (int j = 0; j < 8; j++) {
      wq[j] = Wq[(H_+z0+j)*H_ + tid];
      wk[j] = Wk[(H_+z0+j)*H_ + tid];
      wv[j] = Wv[(H_+z0+j)*H_ + tid];
    }
    #pragma unroll
    for (int j = 0; j < 8; j++) {
      #pragma unroll
      for (int s = 0; s < 16; s++) {
        float zz = zs[s*Z_ + z0 + j];
        accq[s] = fmaf(zz, wq[j], accq[s]);
        acck[s] = fmaf(zz, wk[j], acck[s]);
        accv[s] = fmaf(zz, wv[j], accv[s]);
      }
    }
  }
  #pragma unroll
  for (int s = 0; s < 16; s++) {
    size_t row = ((size_t)b*S_ + st*16 + s)*H_ + tid;
    unsigned short qh = f2bf(accq[s]);
    Qhi[row] = qh;
    Qlo[row] = f2bf(accq[s] - bf2f(qh));
    unsigned short kh = f2bf(acck[s]);
    Khi[row] = kh;
    Klo[row] = f2bf(acck[s] - bf2f(kh));
    vbuf[s][tid] = accv[s];
  }
  __syncthreads();
  unsigned int pk[8];
  #pragma unroll
  for (int j = 0; j < 8; j++)
    pk[j] = pack2(vbuf[2*j][tid], vbuf[2*j+1][tid]);
  uint4* vt4 = reinterpret_cast<uint4*>(Vt + ((size_t)b*H_ + tid)*S_ + st*16);
  vt4[0] = make_uint4(pk[0], pk[1], pk[2], pk[3]);
  vt4[1] = make_uint4(pk[4], pk[5], pk[6], pk[7]);
}

// ---------------------------------------------------------------------------
// k2: QK^T + raw-score store + LANE-LOCAL online (m,l) (no in-loop shuffles —
// shfl = ds_bpermute competes with the LDS pipe feeding MFMA; R12 lesson).
// Cross-lane log-sum-exp combine happens once at the tail. 32 q rows/wave,
// 2 blocks/CU, K double-buffered async DMA, 1 barrier/chunk.
__global__ __launch_bounds__(256, 2) void k2_flash(
    const unsigned short* __restrict__ Qhi, const unsigned short* __restrict__ Qlo,
    const unsigned short* __restrict__ Khi, const unsigned short* __restrict__ Klo,
    const int* __restrict__ mask,
    float* __restrict__ attn, float* __restrict__ Mq, float* __restrict__ Lq) {
  int bb    = blockIdx.x;
  int b     = bb & 7;           // batch = XCD (L2 locality)
  int strip = (bb >> 3) & 15;   // 16 strips of 128 q
  int kq    = bb >> 7;          // k-quarter 0..3
  int qb    = strip*128;
  int k0q   = kq*512;
  int tid  = threadIdx.x;
  int wave = tid >> 6;
  int lane = tid & 63;
  int l15  = lane & 15;
  int quad = lane >> 4;
  int qw   = qb + wave*32;      // this wave's 32-row q base

  __shared__ __align__(16) unsigned short KhiL[2][32*256];   // 32 KB
  __shared__ __align__(16) unsigned short KloL[2][32*256];   // 32 KB

  const unsigned short* KhiB = Khi + (size_t)b*S_*H_;
  const unsigned short* KloB = Klo + (size_t)b*S_*H_;

  int sub = lane >> 5;          // K-DMA: row pair within instr
  int c5  = lane & 31;          // K-DMA: physical 16B slot within 512B row

  auto dma_chunk = [&](int c) {
    int buf = c & 1;
    int kc = k0q + c*CHK;
    #pragma unroll
    for (int t = 0; t < 4; t++) {
      int i = wave*4 + t;                 // 16 x 1KB instrs over 4 waves
      int row = i*2 + sub;                // K row 0..31
      int lslot = c5 ^ ((row & 15) << 1); // data for physical slot c5
      size_t gs = (size_t)(kc + row)*H_ + lslot*8;
      gl_lds16(KhiB + gs, &KhiL[buf][i*512]);
      gl_lds16(KloB + gs, &KloL[buf][i*512]);
    }
  };

  // Q fragments for 2 q-tiles: A[m=l15][k=quad*8+j]
  bf16x8 qh[2][8], ql[2][8];
  #pragma unroll
  for (int qt = 0; qt < 2; qt++) {
    const unsigned short* qhp = Qhi + ((size_t)b*S_ + qw + qt*16 + l15)*H_ + quad*8;
    const unsigned short* qlp = Qlo + ((size_t)b*S_ + qw + qt*16 + l15)*H_ + quad*8;
    #pragma unroll
    for (int dc = 0; dc < 8; dc++) {
      qh[qt][dc] = *reinterpret_cast<const bf16x8*>(qhp + dc*32);
      ql[qt][dc] = *reinterpret_cast<const bf16x8*>(qlp + dc*32);
    }
  }
  int mrow[2][4];
  #pragma unroll
  for (int qt = 0; qt < 2; qt++)
    #pragma unroll
    for (int r = 0; r < 4; r++) mrow[qt][r] = mask[b*S_ + qw + qt*16 + quad*4 + r];

  float m_run[2][4] = {{-1e30f,-1e30f,-1e30f,-1e30f},{-1e30f,-1e30f,-1e30f,-1e30f}};
  float l_run[2][4] = {{0.f,0.f,0.f,0.f},{0.f,0.f,0.f,0.f}};

  dma_chunk(0);
  __syncthreads();

  for (int c = 0; c < NQCH; c++) {
    if (c+1 < NQCH) dma_chunk(c+1);     // other buffer; lands during compute
    int buf = c & 1;
    int kc  = k0q + c*CHK;
    f32x4 sacc[2][2];
    #pragma unroll
    for (int kt = 0; kt < 2; kt++) {
      int row = kt*16 + l15;
      int sw  = (row & 15) << 1;
      const unsigned short* khb = &KhiL[buf][row*256];
      const unsigned short* klb = &KloL[buf][row*256];
      f32x4 a0[2], a1[2];
      #pragma unroll
      for (int qt = 0; qt < 2; qt++) {
        a0[qt] = (f32x4){0.f,0.f,0.f,0.f};
        a1[qt] = (f32x4){0.f,0.f,0.f,0.f};
      }
      #pragma unroll
      for (int dc = 0; dc < 8; dc += 2) {
        int s0 = ((dc*4 + quad) ^ sw) * 8;
        int s1 = (((dc+1)*4 + quad) ^ sw) * 8;
        bf16x8 kh0 = *reinterpret_cast<const bf16x8*>(khb + s0);
        bf16x8 kl0 = *reinterpret_cast<const bf16x8*>(klb + s0);
        bf16x8 kh1 = *reinterpret_cast<const bf16x8*>(khb + s1);
        bf16x8 kl1 = *reinterpret_cast<const bf16x8*>(klb + s1);
        #pragma unroll
        for (int qt = 0; qt < 2; qt++) {   // each K frag feeds both q-tiles
          a0[qt] = __builtin_amdgcn_mfma_f32_16x16x32_bf16(qh[qt][dc],   kh0, a0[qt], 0, 0, 0);
          a1[qt] = __builtin_amdgcn_mfma_f32_16x16x32_bf16(qh[qt][dc+1], kh1, a1[qt], 0, 0, 0);
          a0[qt] = __builtin_amdgcn_mfma_f32_16x16x32_bf16(ql[qt][dc],   kh0, a0[qt], 0, 0, 0);
          a1[qt] = __builtin_amdgcn_mfma_f32_16x16x32_bf16(ql[qt][dc+1], kh1, a1[qt], 0, 0, 0);
          a0[qt] = __builtin_amdgcn_mfma_f32_16x16x32_bf16(qh[qt][dc],   kl0, a0[qt], 0, 0, 0);
          a1[qt] = __builtin_amdgcn_mfma_f32_16x16x32_bf16(qh[qt][dc+1], kl1, a1[qt], 0, 0, 0);
        }
      }
      #pragma unroll
      for (int qt = 0; qt < 2; qt++) sacc[qt][kt] = a0[qt] + a1[qt];
    }
    // raw scores out + lane-local (m,l) update — zero cross-lane ops in-loop
    #pragma unroll
    for (int qt = 0; qt < 2; qt++) {
      #pragma unroll
      for (int r = 0; r < 4; r++) {
        float se0 = mrow[qt][r] ? sacc[qt][0][r]*0.0625f : -1e9f;
        float se1 = mrow[qt][r] ? sacc[qt][1][r]*0.0625f : -1e9f;
        size_t rb = ((size_t)b*S_ + qw + qt*16 + quad*4 + r)*S_ + kc;
        attn[rb + l15]      = se0;
        attn[rb + 16 + l15] = se1;
        float mold = m_run[qt][r];
        float mnew = fmaxf(mold, fmaxf(se0, se1));
        float alpha = __expf(mold - mnew);
        l_run[qt][r] = l_run[qt][r]*alpha + __expf(se0 - mnew) + __expf(se1 - mnew);
        m_run[qt][r] = mnew;
      }
    }
    __syncthreads();   // readers done + DMA(c+1) drained
  }

  // tail: cross-lane log-sum-exp butterfly over the 16 l15 lanes (once)
  #pragma unroll
  for (int qt = 0; qt < 2; qt++) {
    #pragma unroll
    for (int r = 0; r < 4; r++) {
      float m = m_run[qt][r], l = l_run[qt][r];
      #pragma unroll
      for (int d = 1; d <= 8; d <<= 1) {
        float mo = __shfl_xor(m, d);
        float lo = __shfl_xor(l, d);
        float mn = fmaxf(m, mo);
        l = l*__expf(m - mn) + lo*__expf(mo - mn);
        m = mn;
      }
      if (l15 == 0) {
        int idx = kq*BS + b*S_ + qw + qt*16 + quad*4 + r;
        Mq[idx] = m;
        Lq[idx] = l;
      }
    }
  }
}

// ---------------------------------------------------------------------------
// k3a: final fused pass. (m, il) known upfront from Mq/Lq -> single sweep:
// p*il = exp(se-m)*il is written as the FINAL attn (fp32) and packed (already
// normalized) into bf16 P fragments, so AV produces out directly.
__global__ __launch_bounds__(256) void k3a(
    float* __restrict__ attn, const unsigned short* __restrict__ Vt,
    const float* __restrict__ Mq, const float* __restrict__ Lq,
    float* __restrict__ outp) {
  int bb = blockIdx.x;            // grid 256 = 8 b x 32 strips of 64 q
  int b  = bb & 7;
  int qb = (bb >> 3) * 64;
  int tid  = threadIdx.x;
  int wave = tid >> 6;
  int lane = tid & 63;
  int l15  = lane & 15;
  int quad = lane >> 4;
  int qw   = qb + wave*16;

  __shared__ __align__(16) unsigned short VtL[2][256*64];   // 2 x 32 KB

  const unsigned short* VtB = Vt + (size_t)b*H_*S_;
  int gr = b*S_ + qw + l15;       // this lane's q-row
  float m0 = Mq[gr], m1 = Mq[BS+gr], m2 = Mq[2*BS+gr], m3 = Mq[3*BS+gr];
  float m = fmaxf(fmaxf(m0, m1), fmaxf(m2, m3));
  float l = Lq[gr]*__expf(m0-m) + Lq[BS+gr]*__expf(m1-m)
          + Lq[2*BS+gr]*__expf(m2-m) + Lq[3*BS+gr]*__expf(m3-m);
  float il = 1.f / l;

  int hsub = lane >> 3;           // V-DMA: h row within 8
  int slot = lane & 7;            // V-DMA: physical 16B slot within 128B row

  auto dma_v = [&](int c) {       // 64-k chunk -> 32 KB
    int buf = c & 1;
    int kc = c*64;
    #pragma unroll
    for (int t = 0; t < 8; t++) {
      int i = wave*8 + t;         // 32 x 1KB instrs over 4 waves
      int h = i*8 + hsub;
      int lslot = slot ^ (((h >> 2) & 3) << 1);
      gl_lds16(VtB + (size_t)h*S_ + kc + lslot*8, &VtL[buf][i*512]);
    }
  };

  f32x4 acc[16];
  #pragma unroll
  for (int ht = 0; ht < 16; ht++) acc[ht] = (f32x4){0.f, 0.f, 0.f, 0.f};

  float* sp = attn + (size_t)gr*S_ + quad*8;
  dma_v(0);
  float4 s0 = *reinterpret_cast<const float4*>(sp);
  float4 s1 = *reinterpret_cast<const float4*>(sp + 4);
  float4 s2 = *reinterpret_cast<const float4*>(sp + 32);
  float4 s3 = *reinterpret_cast<const float4*>(sp + 36);
  __syncthreads();

  for (int c = 0; c < 32; c++) {
    if (c+1 < 32) dma_v(c+1);
    int buf = c & 1;
    // prefetch next chunk's scores while processing current
    float4 n0, n1, n2, n3;
    if (c+1 < 32) {
      const float* np = sp + (c+1)*64;
      n0 = *reinterpret_cast<const float4*>(np);
      n1 = *reinterpret_cast<const float4*>(np + 4);
      n2 = *reinterpret_cast<const float4*>(np + 32);
      n3 = *reinterpret_cast<const float4*>(np + 36);
    }
    // normalized probabilities (m, il fixed)
    float p0 = __expf(s0.x - m)*il, p1 = __expf(s0.y - m)*il;
    float p2 = __expf(s0.z - m)*il, p3 = __expf(s0.w - m)*il;
    float p4 = __expf(s1.x - m)*il, p5 = __expf(s1.y - m)*il;
    float p6 = __expf(s1.z - m)*il, p7 = __expf(s1.w - m)*il;
    float q0f = __expf(s2.x - m)*il, q1f = __expf(s2.y - m)*il;
    float q2f = __expf(s2.z - m)*il, q3f = __expf(s2.w - m)*il;
    float q4f = __expf(s3.x - m)*il, q5f = __expf(s3.y - m)*il;
    float q6f = __expf(s3.z - m)*il, q7f = __expf(s3.w - m)*il;
    // final attn values (in-place over the raw scores)
    float* ap = sp + c*64;
    *reinterpret_cast<float4*>(ap)      = make_float4(p0, p1, p2, p3);
    *reinterpret_cast<float4*>(ap + 4)  = make_float4(p4, p5, p6, p7);
    *reinterpret_cast<float4*>(ap + 32) = make_float4(q0f, q1f, q2f, q3f);
    *reinterpret_cast<float4*>(ap + 36) = make_float4(q4f, q5f, q6f, q7f);
    // P fragments (already normalized) for AV
    unsigned int pw[4] = {pack2(p0,p1), pack2(p2,p3), pack2(p4,p5), pack2(p6,p7)};
    unsigned int qv[4] = {pack2(q0f,q1f), pack2(q2f,q3f), pack2(q4f,q5f), pack2(q6f,q7f)};
    bf16x8 pa0, pa1;
    memcpy(&pa0, pw, 16);
    memcpy(&pa1, qv, 16);
    int swz = ((l15 >> 2) & 3) << 1;
    #pragma unroll
    for (int ht = 0; ht < 16; ht++) {
      const unsigned short* vb = &VtL[buf][(ht*16 + l15)*64];
      bf16x8 v0 = *reinterpret_cast<const bf16x8*>(vb + (quad ^ swz)*8);
      bf16x8 v1 = *reinterpret_cast<const bf16x8*>(vb + ((4 + quad) ^ swz)*8);
      acc[ht] = __builtin_amdgcn_mfma_f32_16x16x32_bf16(pa0, v0, acc[ht], 0, 0, 0);
      acc[ht] = __builtin_amdgcn_mfma_f32_16x16x32_bf16(pa1, v1, acc[ht], 0, 0, 0);
    }
    s0 = n0; s1 = n1; s2 = n2; s3 = n3;
    __syncthreads();
  }

  // out is already normalized (il folded into P)
  #pragma unroll
  for (int ht = 0; ht < 16; ht++)
    #pragma unroll
    for (int r = 0; r < 4; r++)
      outp[((size_t)b*S_ + qw + quad*4 + r)*H_ + ht*16 + l15] = acc[ht][r];
}

// ---------------------------------------------------------------------------
extern "C" void kernel_launch(void* const* d_in, const int* in_sizes, int n_in,
                              void* d_out, int out_size, void* d_ws, size_t ws_size,
                              hipStream_t stream) {
  const float* enc = (const float*)d_in[0];
  // d_in[1] = decoder_hidden_state: unused by the reference
  const float* z   = (const float*)d_in[2];
  const int* mask  = (const int*)d_in[3];
  const float* Wq  = (const float*)d_in[4];
  const float* Wk  = (const float*)d_in[5];
  const float* Wv  = (const float*)d_in[6];

  char* ws = (char*)d_ws;
  const size_t MB = 1024*1024;
  unsigned short* Qhi = (unsigned short*)(ws);
  unsigned short* Qlo = (unsigned short*)(ws +  8*MB);
  unsigned short* Khi = (unsigned short*)(ws + 16*MB);
  unsigned short* Klo = (unsigned short*)(ws + 24*MB);
  unsigned short* Vt  = (unsigned short*)(ws + 32*MB);
  float* q0 = (float*)(ws + 40*MB);
  float* k0 = q0 + B_*H_;
  float* v0 = k0 + B_*H_;
  float* Mq = (float*)(ws + 41*MB);                 // [4][B*S] = 256 KB
  float* Lq = (float*)(ws + 41*MB + 512*1024);      // [4][B*S] = 256 KB

  float* outp = (float*)d_out;
  float* attn = outp + (size_t)B_*S_*H_;

  k0_base<<<B_, 256, 0, stream>>>(enc, Wq, Wk, Wv, q0, k0, v0);
  k1_prep<<<B_*(S_/16), 256, 0, stream>>>(z, Wq, Wk, Wv, q0, k0, v0,
                                          Qhi, Qlo, Khi, Klo, Vt);
  k2_flash<<<B_*(S_/128)*4, 256, 0, stream>>>(Qhi, Qlo, Khi, Klo, mask,
                                              attn, Mq, Lq);
  k3a<<<B_*(S_/64), 256, 0, stream>>>(attn, Vt, Mq, Lq, outp);
}